// Round 21
// baseline (65.997 us; speedup 1.0000x reference)
//
#include <hip/hip_runtime.h>
#include <cfloat>

// Problem constants (fixed by setup_inputs)
#define C_DIM   256
#define HW      1024
#define N_ROWS  32768
#define K_CODES 1024
#define ROWS    64            // rows per workgroup
#define NSUPER  16            // 16 superchunks x 64 codes (2 x 32-code chunks)
#define SUPER_BYTES 32768     // 64 codes * 256 * 2B fp16
#define LISTCAP 128           // per-wave candidate list
#define DELTA   0.008f
#define CMASK   0xFFFFFFE0u   // clear low 5 mantissa bits for chunk-id packing
#define ZSTRIDE 260           // zt padded stride (floats)

#define OUT_ELEMS 8388608
#define LOSS_OFF  8388608
#define IDX_OFF   8388611

typedef _Float16 half8 __attribute__((ext_vector_type(8)));
typedef _Float16 f16x4 __attribute__((ext_vector_type(4)));
typedef float    f32x4 __attribute__((ext_vector_type(4)));

#define AS1 __attribute__((address_space(1)))
#define AS3 __attribute__((address_space(3)))

// dynamic LDS layout (bytes).
// zt [64][260] f32 (66560B) occupies [0,66560) during the prologue ONLY;
// ebuf (2 shared superbufs * 32768 = 65536B) aliases it for the sweep;
// qt [32][258] f32 (33024B) aliases it again in the output tail.
#define OFF_EBUF  0
#define OFF_EN    66560                // 1024*4 -> 70656  (clear of zt/ebuf)
#define OFF_S32   70656                // 64*4 -> 70912
#define OFF_M1W   70912                // 2*64*4 -> 71424
#define OFF_THR   71424                // 64*4 -> 71680
#define OFF_RES   71680                // 64*8 -> 72192
#define OFF_FIDX  72192                // 64*4 -> 72448
#define OFF_LCNT  72448                // pad -> 72704
#define OFF_LMETA 72704                // 4*128*4 -> 74752
#define SMEM_BYTES 74752               // x2 = 149504 <= 163840 -> 2 blocks/CU

#define QT_STRIDE 258

// min across the 16-lane row group (lanes sharing lane>>4)
#define DPP_MIN(x, ctrl) fminf((x), __int_as_float(__builtin_amdgcn_update_dpp(0, __float_as_int(x), (ctrl), 0xf, 0xf, true)))

// Kernel 1: codebook prep — fp32 norms (fp64-accurate) + fp16 copy, kk-major layout.
// 16-code group g = k/16 (8192 B each); within group:
//   byte = (c/32)*1024 + ((c/8)%4)*256 + (k%16)*16 + (c%8)*2
// Superchunk i = groups {4i..4i+3} = bytes [i*32768, (i+1)*32768).
__global__ void prep_kernel(const float* __restrict__ cb, float* __restrict__ enorm,
                            char* __restrict__ cb16) {
    int k = blockIdx.x * 4 + (threadIdx.x >> 6);
    int lane = threadIdx.x & 63;
    int c0 = lane * 4;
    float4 v = *(const float4*)(cb + k * C_DIM + c0);
    double s = (double)v.x * v.x + (double)v.y * v.y + (double)v.z * v.z + (double)v.w * v.w;
    #pragma unroll
    for (int m = 1; m < 64; m <<= 1) s += __shfl_xor(s, m, 64);
    if (lane == 0) enorm[k] = (float)s;
    f16x4 h;
    h[0] = (_Float16)v.x; h[1] = (_Float16)v.y; h[2] = (_Float16)v.z; h[3] = (_Float16)v.w;
    int dst = ((k >> 4) << 13) + ((c0 >> 5) << 10) + (((c0 >> 3) & 3) << 8)
            + ((k & 15) << 4) + ((c0 & 7) << 1);
    *(f16x4*)(cb16 + dst) = h;
}

// Kernel 2: R20 structure with the sweep reorganized to 16 iterations over 64-code
// superchunks in a 2x32KB shared double-buffer: ONE barrier + ONE vmcnt per 2 chunks
// (halves per-iteration sync overhead). Loads waited on are a full iteration old.
// Packed top-2 + exact fp64+fp32-sim rescore unchanged.
__global__ __launch_bounds__(256, 2) void vq_main(
    const float* __restrict__ x, const float* __restrict__ cb,
    const float* __restrict__ enorm_g, const char* __restrict__ cb16,
    float* __restrict__ out, float* __restrict__ idx_out, float* __restrict__ t2_out)
{
    extern __shared__ char smem[];
    float* zt      = (float*)(smem + OFF_EBUF);   // prologue-phase alias
    float* qt      = (float*)(smem + OFF_EBUF);   // tail-phase alias
    char*  ebuf    = smem + OFF_EBUF;             // sweep-phase: 2 x 32KB shared
    float* en_lds  = (float*)(smem + OFF_EN);
    float* S32     = (float*)(smem + OFF_S32);
    float* m1w     = (float*)(smem + OFF_M1W);    // [wc][64]
    float* thr     = (float*)(smem + OFF_THR);
    unsigned long long* res = (unsigned long long*)(smem + OFF_RES);
    int*   fidx    = (int*)(smem + OFF_FIDX);
    int*   lcnt    = (int*)(smem + OFF_LCNT);
    unsigned int* lmeta = (unsigned int*)(smem + OFF_LMETA);

    const int t    = threadIdx.x;
    const int lane = t & 63;
    const int wv   = t >> 6;
    const int wr   = wv >> 1;          // row half: rows wr*32 .. wr*32+31
    const int wc   = wv & 1;           // code half within each 32-code chunk
    const int l15  = lane & 15;
    const int l4   = lane >> 4;
    const int row0 = blockIdx.x * ROWS;
    const int b    = row0 >> 10;
    const int hw0  = row0 & 1023;
    const float* xb = x + b * (C_DIM * HW) + hw0;

    const int qofs = wv * 8192;        // wave's staging quarter within a superchunk

    // ---- phase 1: stage z tile (coalesced float4, 4x4 transpose) + enorm ----
    {
        int g   = t & 15;      // rows 4g..4g+3
        int cb4 = t >> 4;      // c-block
        for (int cc = cb4 * 4; cc < C_DIM; cc += 64) {
            float4 v0 = *(const float4*)(xb + (cc + 0) * HW + g * 4);
            float4 v1 = *(const float4*)(xb + (cc + 1) * HW + g * 4);
            float4 v2 = *(const float4*)(xb + (cc + 2) * HW + g * 4);
            float4 v3 = *(const float4*)(xb + (cc + 3) * HW + g * 4);
            *(float4*)&zt[(g * 4 + 0) * ZSTRIDE + cc] = make_float4(v0.x, v1.x, v2.x, v3.x);
            *(float4*)&zt[(g * 4 + 1) * ZSTRIDE + cc] = make_float4(v0.y, v1.y, v2.y, v3.y);
            *(float4*)&zt[(g * 4 + 2) * ZSTRIDE + cc] = make_float4(v0.z, v1.z, v2.z, v3.z);
            *(float4*)&zt[(g * 4 + 3) * ZSTRIDE + cc] = make_float4(v0.w, v1.w, v2.w, v3.w);
        }
        *(float4*)&en_lds[t * 4] = *(const float4*)(enorm_g + t * 4);
        if (t < 4) lcnt[t] = 0;
    }
    __syncthreads();

    // ---- phase 2: fp64 S32 + A fragments from zt (zt dies after this) ----
    {
        int r = t >> 2, seg = t & 3;
        const float* zr = &zt[r * ZSTRIDE + seg * 64];
        double s = 0.0;
        for (int c = 0; c < 64; c += 4) {
            float4 v = *(const float4*)(zr + c);
            s = fma((double)v.x, (double)v.x, s);
            s = fma((double)v.y, (double)v.y, s);
            s = fma((double)v.z, (double)v.z, s);
            s = fma((double)v.w, (double)v.w, s);
        }
        s += __shfl_xor(s, 1, 64);
        s += __shfl_xor(s, 2, 64);
        if (seg == 0) S32[r] = (float)s;
    }

    half8 af[2][8];                    // this wave's 32 rows, fp16(-2z)
    #pragma unroll
    for (int rt = 0; rt < 2; rt++) {
        int row = wr * 32 + rt * 16 + l15;
        #pragma unroll
        for (int kk = 0; kk < 8; kk++) {
            int c0 = kk * 32 + l4 * 8;
            float4 a  = *(const float4*)&zt[row * ZSTRIDE + c0];
            float4 a2 = *(const float4*)&zt[row * ZSTRIDE + c0 + 4];
            half8 h;
            h[0] = (_Float16)(-2.0f * a.x);  h[1] = (_Float16)(-2.0f * a.y);
            h[2] = (_Float16)(-2.0f * a.z);  h[3] = (_Float16)(-2.0f * a.w);
            h[4] = (_Float16)(-2.0f * a2.x); h[5] = (_Float16)(-2.0f * a2.y);
            h[6] = (_Float16)(-2.0f * a2.z); h[7] = (_Float16)(-2.0f * a2.w);
            af[rt][kk] = h;
        }
    }
    __syncthreads();   // zt dead; ebuf may now overwrite it (also drains vmcnt)

    // ---- issue this wave's QUARTER of superchunk 0 into buf 0 ----
    #pragma unroll
    for (int i = 0; i < 8; i++) {
        __builtin_amdgcn_global_load_lds((const AS1 unsigned int*)(cb16 + qofs + i * 1024 + lane * 16),
                                         (AS3 unsigned int*)(ebuf + qofs + i * 1024), 16, 0, 0);
    }

    const int bbase  = (wc << 13) + (l4 << 8) + (l15 << 4);   // base within a 16KB chunk
    const int enbase = wc * 16 + l15;                          // + ch*32

    // ====== SWEEP: 16 superchunks; 1 barrier + 1 vmcnt per 64 codes ======
    float u1[2][4], u2[2][4];
    #pragma unroll
    for (int rt = 0; rt < 2; rt++)
        #pragma unroll
        for (int r2 = 0; r2 < 4; r2++) { u1[rt][r2] = FLT_MAX; u2[rt][r2] = FLT_MAX; }

    for (int sc = 0; sc < NSUPER; sc++) {
        // superchunk sc's loads were issued a full iteration ago (prologue for sc=0)
        asm volatile("s_waitcnt vmcnt(0)" ::: "memory");
        __builtin_amdgcn_sched_barrier(0);
        __builtin_amdgcn_s_barrier();       // all 4 waves' quarters landed
        __builtin_amdgcn_sched_barrier(0);

        const char* ebc = ebuf + (sc & 1) * SUPER_BYTES;

        // refill buf (sc+1)&1 with superchunk sc+1 (its last reads preceded this barrier)
        if (sc + 1 < NSUPER) {
            const char* src = cb16 + (sc + 1) * SUPER_BYTES + qofs;
            char* dst = ebuf + ((sc + 1) & 1) * SUPER_BYTES + qofs;
            #pragma unroll
            for (int i = 0; i < 8; i++) {
                __builtin_amdgcn_global_load_lds((const AS1 unsigned int*)(src + i * 1024 + lane * 16),
                                                 (AS3 unsigned int*)(dst + i * 1024), 16, 0, 0);
            }
        }

        // ---- chunk 2*sc (first 16KB half) ----
        {
            const int ch = 2 * sc;
            half8 bf[8];
            #pragma unroll
            for (int kk = 0; kk < 8; kk++)
                bf[kk] = *(const half8*)(ebc + bbase + (kk << 10));
            const float en = en_lds[enbase + ch * 32];
            f32x4 acc0 = {en, en, en, en};
            f32x4 acc1 = {en, en, en, en};
            #pragma unroll
            for (int kk = 0; kk < 8; kk++) {
                acc0 = __builtin_amdgcn_mfma_f32_16x16x32_f16(af[0][kk], bf[kk], acc0, 0, 0, 0);
                acc1 = __builtin_amdgcn_mfma_f32_16x16x32_f16(af[1][kk], bf[kk], acc1, 0, 0, 0);
            }
            #pragma unroll
            for (int r2 = 0; r2 < 4; r2++) {
                float a0 = __uint_as_float((__float_as_uint(acc0[r2]) & CMASK) | (unsigned)ch);
                u2[0][r2] = __builtin_amdgcn_fmed3f(a0, u1[0][r2], u2[0][r2]);
                u1[0][r2] = fminf(u1[0][r2], a0);
                float a1 = __uint_as_float((__float_as_uint(acc1[r2]) & CMASK) | (unsigned)ch);
                u2[1][r2] = __builtin_amdgcn_fmed3f(a1, u1[1][r2], u2[1][r2]);
                u1[1][r2] = fminf(u1[1][r2], a1);
            }
        }
        // ---- chunk 2*sc+1 (second 16KB half) ----
        {
            const int ch = 2 * sc + 1;
            half8 bf[8];
            #pragma unroll
            for (int kk = 0; kk < 8; kk++)
                bf[kk] = *(const half8*)(ebc + 16384 + bbase + (kk << 10));
            const float en = en_lds[enbase + ch * 32];
            f32x4 acc0 = {en, en, en, en};
            f32x4 acc1 = {en, en, en, en};
            #pragma unroll
            for (int kk = 0; kk < 8; kk++) {
                acc0 = __builtin_amdgcn_mfma_f32_16x16x32_f16(af[0][kk], bf[kk], acc0, 0, 0, 0);
                acc1 = __builtin_amdgcn_mfma_f32_16x16x32_f16(af[1][kk], bf[kk], acc1, 0, 0, 0);
            }
            #pragma unroll
            for (int r2 = 0; r2 < 4; r2++) {
                float a0 = __uint_as_float((__float_as_uint(acc0[r2]) & CMASK) | (unsigned)ch);
                u2[0][r2] = __builtin_amdgcn_fmed3f(a0, u1[0][r2], u2[0][r2]);
                u1[0][r2] = fminf(u1[0][r2], a0);
                float a1 = __uint_as_float((__float_as_uint(acc1[r2]) & CMASK) | (unsigned)ch);
                u2[1][r2] = __builtin_amdgcn_fmed3f(a1, u1[1][r2], u2[1][r2]);
                u1[1][r2] = fminf(u1[1][r2], a1);
            }
        }
    }

    // ---- one-time reduce: DPP over 16 lanes -> per-row wave min; cross-wave merge ----
    #pragma unroll
    for (int rt = 0; rt < 2; rt++) {
        #pragma unroll
        for (int r2 = 0; r2 < 4; r2++) {
            float m = u1[rt][r2];
            m = DPP_MIN(m, 0xB1);
            m = DPP_MIN(m, 0x4E);
            m = DPP_MIN(m, 0x141);
            m = DPP_MIN(m, 0x140);   // min over this wave's 16 code-columns
            if (l15 == 0) m1w[wc * 64 + wr * 32 + rt * 16 + l4 * 4 + r2] = m;
        }
    }
    __syncthreads();
    if (t < 64) {
        thr[t] = fminf(m1w[t], m1w[64 + t]) + DELTA;   // min over all 1024 codes + delta
        res[t] = ~0ull;
    }
    __syncthreads();

    // ---- push candidates from register top-2 (once, tiny) ----
    #pragma unroll
    for (int rt = 0; rt < 2; rt++) {
        #pragma unroll
        for (int r2 = 0; r2 < 4; r2++) {
            int row_l = wr * 32 + rt * 16 + l4 * 4 + r2;
            float tr = thr[row_l];
            if (u1[rt][r2] < tr) {
                int ch1 = (int)(__float_as_uint(u1[rt][r2]) & 31u);
                int code = ch1 * 32 + wc * 16 + l15;
                int slot = atomicAdd(&lcnt[wv], 1);
                if (slot < LISTCAP)
                    lmeta[wv * LISTCAP + slot] = ((unsigned)row_l << 16) | (unsigned)code;
            }
            if (u2[rt][r2] < tr) {
                int ch2 = (int)(__float_as_uint(u2[rt][r2]) & 31u);
                int code = ch2 * 32 + wc * 16 + l15;
                int slot = atomicAdd(&lcnt[wv], 1);
                if (slot < LISTCAP)
                    lmeta[wv * LISTCAP + slot] = ((unsigned)row_l << 16) | (unsigned)code;
            }
        }
    }
    __syncthreads();

    // ---- rescore survivors: fp64 dot (z re-read from global) -> fp32 ref sim ----
    {
        int n = lcnt[wv]; if (n > LISTCAP) n = LISTCAP;
        for (int base = 0; base < n; base += 4) {
            int it = base + l4;
            if (it < n) {
                unsigned meta = lmeta[wv * LISTCAP + it];
                int row  = (int)(meta >> 16);
                int code = (int)(meta & 1023u);
                const float* xr = xb + row;            // element c at xr[c*HW]
                const float* er = cb + code * C_DIM;
                double acc = 0.0;
                #pragma unroll
                for (int s2 = 0; s2 < 16; s2++) {
                    int c = l15 + 16 * s2;
                    acc = fma((double)xr[(size_t)c * HW], (double)er[c], acc);
                }
                acc += __shfl_xor(acc, 1, 64);
                acc += __shfl_xor(acc, 2, 64);
                acc += __shfl_xor(acc, 4, 64);
                acc += __shfl_xor(acc, 8, 64);
                if (l15 == 0) {
                    float Mf = (float)acc;
                    float t2 = __fadd_rn(__fsub_rn(S32[row], __fmul_rn(2.0f, Mf)), en_lds[code]);
                    unsigned long long pk =
                        ((unsigned long long)__float_as_uint(t2) << 32) | (unsigned long long)(unsigned)code;
                    atomicMin(&res[row], pk);
                }
            }
        }
    }
    __syncthreads();

    if (t < 64) {
        unsigned long long v = res[t];
        int code = (int)(v & 1023u);
        fidx[t] = code;
        idx_out[row0 + t] = (float)code;
        t2_out[row0 + t] = __uint_as_float((unsigned)(v >> 32));
    }

    // ---- quantized output (NCHW) via LDS bounce: coalesced reads AND stores ----
    float* ob = out + b * (C_DIM * HW) + hw0;
    #pragma unroll
    for (int half = 0; half < 2; half++) {
        __syncthreads();   // fidx ready (first); prior half's stores done (second)
        for (int idx = t; idx < 32 * 64; idx += 256) {
            int r  = idx >> 6;         // 0..31
            int c4 = idx & 63;
            const float* er = cb + fidx[half * 32 + r] * C_DIM;
            *(float4*)&qt[r * QT_STRIDE + c4 * 4] = *(const float4*)(er + c4 * 4);
        }
        __syncthreads();
        int rr = t & 31;
        int cg = t >> 5;               // 0..7
        for (int cc = cg; cc < C_DIM; cc += 8) {
            ob[cc * HW + half * 32 + rr] = qt[rr * QT_STRIDE + cc];
        }
    }
}

// Kernel 3: deterministic loss reduction over per-row t2
__global__ void loss_kernel(const float* __restrict__ t2min, float* __restrict__ losses) {
    __shared__ double sh[256];
    int t = threadIdx.x;
    double a = 0.0;
    const int per = N_ROWS / 256;
    for (int i = t * per; i < t * per + per; i++) a += (double)t2min[i];
    sh[t] = a;
    __syncthreads();
    for (int s = 128; s > 0; s >>= 1) {
        if (t < s) sh[t] += sh[t + s];
        __syncthreads();
    }
    if (t == 0) {
        double M = sh[0] / (double)OUT_ELEMS;
        losses[0] = (float)(1.25 * M);   // quantizer_loss
        losses[1] = (float)(0.25 * M);   // e_latent_loss
        losses[2] = (float)(M);          // q_latent_loss
    }
}

extern "C" void kernel_launch(void* const* d_in, const int* in_sizes, int n_in,
                              void* d_out, int out_size, void* d_ws, size_t ws_size,
                              hipStream_t stream) {
    const float* x  = (const float*)d_in[0];
    const float* cb = (const float*)d_in[1];
    float* out     = (float*)d_out;
    float* losses  = out + LOSS_OFF;
    float* idx_out = out + IDX_OFF;

    char*  cb16     = (char*)d_ws;                               // 524288 B
    float* t2ws     = (float*)((char*)d_ws + 524288);            // 131072 B
    float* enorm_ws = (float*)((char*)d_ws + 524288 + 131072);   // 4096 B

    hipFuncSetAttribute(reinterpret_cast<const void*>(vq_main),
                        hipFuncAttributeMaxDynamicSharedMemorySize, SMEM_BYTES);

    prep_kernel<<<K_CODES / 4, 256, 0, stream>>>(cb, enorm_ws, cb16);
    vq_main<<<N_ROWS / ROWS, 256, SMEM_BYTES, stream>>>(x, cb, enorm_ws, cb16, out, idx_out, t2ws);
    loss_kernel<<<1, 256, 0, stream>>>(t2ws, losses);
}

// Round 22
// 65.325 us; speedup vs baseline: 1.0103x; 1.0103x over previous
//
#include <hip/hip_runtime.h>
#include <cfloat>

// Problem constants (fixed by setup_inputs)
#define C_DIM   256
#define HW      1024
#define N_ROWS  32768
#define K_CODES 1024
#define ROWS    64            // rows per workgroup
#define NCHUNK  32            // 32 shared chunks x 32 codes
#define CHUNK_BYTES 16384     // 32 codes * 256 * 2B fp16 (shared by all 8 waves)
#define LISTCAP 128           // per-wave candidate list
#define DELTA   0.008f
#define CMASK   0xFFFFFFE0u   // clear low 5 mantissa bits for chunk-id packing
#define ZSTRIDE 260           // zt padded stride (floats)

#define OUT_ELEMS 8388608
#define LOSS_OFF  8388608
#define IDX_OFF   8388611

typedef _Float16 half8 __attribute__((ext_vector_type(8)));
typedef _Float16 f16x4 __attribute__((ext_vector_type(4)));
typedef float    f32x4 __attribute__((ext_vector_type(4)));

#define AS1 __attribute__((address_space(1)))
#define AS3 __attribute__((address_space(3)))

// dynamic LDS layout (bytes).
// zt [64][260] f32 (66560B) occupies [0,66560) during the prologue ONLY;
// ebuf (3 shared bufs * 16384 = 49152B) aliases it for the sweep;
// qt [32][258] f32 (33024B) aliases it again in the output tail.
#define OFF_EBUF  0
#define OFF_EN    66560                // 1024*4 -> 70656  (clear of zt/ebuf)
#define OFF_S32   70656                // 64*4 -> 70912
#define OFF_M1W   70912                // 2*64*4 -> 71424
#define OFF_THR   71424                // 64*4 -> 71680
#define OFF_RES   71680                // 64*8 -> 72192
#define OFF_FIDX  72192                // 64*4 -> 72448
#define OFF_LCNT  72448                // pad -> 72704
#define OFF_LMETA 72704                // 8*128*4 -> 76800
#define SMEM_BYTES 76800               // x2 = 153600 <= 163840 -> 2 blocks/CU

#define QT_STRIDE 258

// min across the 16-lane row group (lanes sharing lane>>4)
#define DPP_MIN(x, ctrl) fminf((x), __int_as_float(__builtin_amdgcn_update_dpp(0, __float_as_int(x), (ctrl), 0xf, 0xf, true)))

// Kernel 1: codebook prep — fp32 norms (fp64-accurate) + fp16 copy, kk-major layout.
// 16-code group g = k/16 (8192 B each); within group:
//   byte = (c/32)*1024 + ((c/8)%4)*256 + (k%16)*16 + (c%8)*2
// Shared 32-code chunk ch = groups {2ch, 2ch+1} (wc halves).
__global__ void prep_kernel(const float* __restrict__ cb, float* __restrict__ enorm,
                            char* __restrict__ cb16) {
    int k = blockIdx.x * 4 + (threadIdx.x >> 6);
    int lane = threadIdx.x & 63;
    int c0 = lane * 4;
    float4 v = *(const float4*)(cb + k * C_DIM + c0);
    double s = (double)v.x * v.x + (double)v.y * v.y + (double)v.z * v.z + (double)v.w * v.w;
    #pragma unroll
    for (int m = 1; m < 64; m <<= 1) s += __shfl_xor(s, m, 64);
    if (lane == 0) enorm[k] = (float)s;
    f16x4 h;
    h[0] = (_Float16)v.x; h[1] = (_Float16)v.y; h[2] = (_Float16)v.z; h[3] = (_Float16)v.w;
    int dst = ((k >> 4) << 13) + ((c0 >> 5) << 10) + (((c0 >> 3) & 3) << 8)
            + ((k & 15) << 4) + ((c0 & 7) << 1);
    *(f16x4*)(cb16 + dst) = h;
}

// Kernel 2: 8-wave (512-thread) variant of R19/R20: wave = 16 rows x 512 codes
// (af[8], 8 MFMA/chunk), 16 waves/CU = 4 waves/SIMD for latency hiding.
// Shared triple-buffered staging (each wave issues eighths, counted vmcnt(2));
// kk-major ds_reads; packed top-2; exact fp64+fp32-sim rescore.
__global__ __launch_bounds__(512, 4) void vq_main(
    const float* __restrict__ x, const float* __restrict__ cb,
    const float* __restrict__ enorm_g, const char* __restrict__ cb16,
    float* __restrict__ out, float* __restrict__ idx_out, float* __restrict__ t2_out)
{
    extern __shared__ char smem[];
    float* zt      = (float*)(smem + OFF_EBUF);   // prologue-phase alias
    float* qt      = (float*)(smem + OFF_EBUF);   // tail-phase alias
    char*  ebuf    = smem + OFF_EBUF;             // sweep-phase: 3 x 16KB shared
    float* en_lds  = (float*)(smem + OFF_EN);
    float* S32     = (float*)(smem + OFF_S32);
    float* m1w     = (float*)(smem + OFF_M1W);    // [wc][64]
    float* thr     = (float*)(smem + OFF_THR);
    unsigned long long* res = (unsigned long long*)(smem + OFF_RES);
    int*   fidx    = (int*)(smem + OFF_FIDX);
    int*   lcnt    = (int*)(smem + OFF_LCNT);
    unsigned int* lmeta = (unsigned int*)(smem + OFF_LMETA);

    const int t    = threadIdx.x;
    const int lane = t & 63;
    const int wv   = t >> 6;           // 0..7
    const int wr   = wv >> 1;          // row group: rows wr*16 .. wr*16+15
    const int wc   = wv & 1;           // code half within each 32-code chunk
    const int l15  = lane & 15;
    const int l4   = lane >> 4;
    const int row0 = blockIdx.x * ROWS;
    const int b    = row0 >> 10;
    const int hw0  = row0 & 1023;
    const float* xb = x + b * (C_DIM * HW) + hw0;

    const int qofs = wv * 2048;        // wave's staging eighth within a 16KB chunk

    // ---- phase 1: stage z tile (coalesced float4, 4x4 transpose) + enorm ----
    {
        int g   = t & 15;      // rows 4g..4g+3
        int cb4 = t >> 4;      // 0..31
        for (int cc = cb4 * 4; cc < C_DIM; cc += 128) {
            float4 v0 = *(const float4*)(xb + (cc + 0) * HW + g * 4);
            float4 v1 = *(const float4*)(xb + (cc + 1) * HW + g * 4);
            float4 v2 = *(const float4*)(xb + (cc + 2) * HW + g * 4);
            float4 v3 = *(const float4*)(xb + (cc + 3) * HW + g * 4);
            *(float4*)&zt[(g * 4 + 0) * ZSTRIDE + cc] = make_float4(v0.x, v1.x, v2.x, v3.x);
            *(float4*)&zt[(g * 4 + 1) * ZSTRIDE + cc] = make_float4(v0.y, v1.y, v2.y, v3.y);
            *(float4*)&zt[(g * 4 + 2) * ZSTRIDE + cc] = make_float4(v0.z, v1.z, v2.z, v3.z);
            *(float4*)&zt[(g * 4 + 3) * ZSTRIDE + cc] = make_float4(v0.w, v1.w, v2.w, v3.w);
        }
        if (t < 256) *(float4*)&en_lds[t * 4] = *(const float4*)(enorm_g + t * 4);
        if (t < 8) lcnt[t] = 0;
    }
    __syncthreads();

    // ---- phase 2: fp64 S32 (first 4 waves) + A fragments (all waves) ----
    if (t < 256) {
        int r = t >> 2, seg = t & 3;
        const float* zr = &zt[r * ZSTRIDE + seg * 64];
        double s = 0.0;
        for (int c = 0; c < 64; c += 4) {
            float4 v = *(const float4*)(zr + c);
            s = fma((double)v.x, (double)v.x, s);
            s = fma((double)v.y, (double)v.y, s);
            s = fma((double)v.z, (double)v.z, s);
            s = fma((double)v.w, (double)v.w, s);
        }
        s += __shfl_xor(s, 1, 64);
        s += __shfl_xor(s, 2, 64);
        if (seg == 0) S32[r] = (float)s;
    }

    half8 af[8];                       // this wave's 16 rows, fp16(-2z)
    {
        int row = wr * 16 + l15;
        #pragma unroll
        for (int kk = 0; kk < 8; kk++) {
            int c0 = kk * 32 + l4 * 8;
            float4 a  = *(const float4*)&zt[row * ZSTRIDE + c0];
            float4 a2 = *(const float4*)&zt[row * ZSTRIDE + c0 + 4];
            half8 h;
            h[0] = (_Float16)(-2.0f * a.x);  h[1] = (_Float16)(-2.0f * a.y);
            h[2] = (_Float16)(-2.0f * a.z);  h[3] = (_Float16)(-2.0f * a.w);
            h[4] = (_Float16)(-2.0f * a2.x); h[5] = (_Float16)(-2.0f * a2.y);
            h[6] = (_Float16)(-2.0f * a2.z); h[7] = (_Float16)(-2.0f * a2.w);
            af[kk] = h;
        }
    }
    __syncthreads();   // zt dead; ebuf may now overwrite it (also drains vmcnt)

    // ---- issue this wave's EIGHTH of chunks 0,1 into shared bufs 0,1 ----
    #pragma unroll
    for (int c2 = 0; c2 < 2; c2++) {
        const char* src = cb16 + c2 * CHUNK_BYTES + qofs;
        char* dst = ebuf + c2 * CHUNK_BYTES + qofs;
        #pragma unroll
        for (int i = 0; i < 2; i++) {
            __builtin_amdgcn_global_load_lds((const AS1 unsigned int*)(src + i * 1024 + lane * 16),
                                             (AS3 unsigned int*)(dst + i * 1024), 16, 0, 0);
        }
    }

    const int bbase  = (wc << 13) + (l4 << 8) + (l15 << 4);   // read base in a chunk
    const int enbase = wc * 16 + l15;                          // + ch*32

    // ====== SINGLE SWEEP: 32 shared chunks; 1 barrier/iter; packed top-2 ======
    float u1[4], u2[4];
    #pragma unroll
    for (int r2 = 0; r2 < 4; r2++) { u1[r2] = FLT_MAX; u2[r2] = FLT_MAX; }

    int r3 = 0;                        // read buffer index (ch % 3)
    for (int ch = 0; ch < NCHUNK; ch++) {
        if (ch == NCHUNK - 1) { asm volatile("s_waitcnt vmcnt(0)" ::: "memory"); }
        else                  { asm volatile("s_waitcnt vmcnt(2)" ::: "memory"); }
        __builtin_amdgcn_sched_barrier(0);
        __builtin_amdgcn_s_barrier();       // all 8 waves' eighths of chunk ch landed
        __builtin_amdgcn_sched_barrier(0);

        const char* ebc = ebuf + r3 * CHUNK_BYTES;
        half8 bf[8];
        #pragma unroll
        for (int kk = 0; kk < 8; kk++)
            bf[kk] = *(const half8*)(ebc + bbase + (kk << 10));

        // refill buf (ch+2)%3 (read finished at iter ch-1, before this barrier)
        if (ch + 2 < NCHUNK) {
            int w3 = r3 + 2; if (w3 >= 3) w3 -= 3;
            const char* src = cb16 + (ch + 2) * CHUNK_BYTES + qofs;
            char* dst = ebuf + w3 * CHUNK_BYTES + qofs;
            #pragma unroll
            for (int i = 0; i < 2; i++) {
                __builtin_amdgcn_global_load_lds((const AS1 unsigned int*)(src + i * 1024 + lane * 16),
                                                 (AS3 unsigned int*)(dst + i * 1024), 16, 0, 0);
            }
        }

        const float en = en_lds[enbase + ch * 32];
        f32x4 acc = {en, en, en, en};      // ||e||^2 folded into C-in
        #pragma unroll
        for (int kk = 0; kk < 8; kk++)
            acc = __builtin_amdgcn_mfma_f32_16x16x32_f16(af[kk], bf[kk], acc, 0, 0, 0);

        // packed top-2: chunk id in low 5 mantissa bits (<=2e-6 perturbation << DELTA)
        #pragma unroll
        for (int r2 = 0; r2 < 4; r2++) {
            float a0 = __uint_as_float((__float_as_uint(acc[r2]) & CMASK) | (unsigned)ch);
            u2[r2] = __builtin_amdgcn_fmed3f(a0, u1[r2], u2[r2]);
            u1[r2] = fminf(u1[r2], a0);
        }

        r3 += 1; if (r3 >= 3) r3 -= 3;
    }

    // ---- one-time reduce: DPP over 16 lanes -> per-row wave min; cross-wave merge ----
    #pragma unroll
    for (int r2 = 0; r2 < 4; r2++) {
        float m = u1[r2];
        m = DPP_MIN(m, 0xB1);
        m = DPP_MIN(m, 0x4E);
        m = DPP_MIN(m, 0x141);
        m = DPP_MIN(m, 0x140);   // min over this wave's 16 code-columns
        if (l15 == 0) m1w[wc * 64 + wr * 16 + l4 * 4 + r2] = m;
    }
    __syncthreads();
    if (t < 64) {
        thr[t] = fminf(m1w[t], m1w[64 + t]) + DELTA;   // min over all 1024 codes + delta
        res[t] = ~0ull;
    }
    __syncthreads();

    // ---- push candidates from register top-2 (once, tiny) ----
    #pragma unroll
    for (int r2 = 0; r2 < 4; r2++) {
        int row_l = wr * 16 + l4 * 4 + r2;
        float tr = thr[row_l];
        if (u1[r2] < tr) {
            int ch1 = (int)(__float_as_uint(u1[r2]) & 31u);
            int code = ch1 * 32 + wc * 16 + l15;
            int slot = atomicAdd(&lcnt[wv], 1);
            if (slot < LISTCAP)
                lmeta[wv * LISTCAP + slot] = ((unsigned)row_l << 16) | (unsigned)code;
        }
        if (u2[r2] < tr) {
            int ch2 = (int)(__float_as_uint(u2[r2]) & 31u);
            int code = ch2 * 32 + wc * 16 + l15;
            int slot = atomicAdd(&lcnt[wv], 1);
            if (slot < LISTCAP)
                lmeta[wv * LISTCAP + slot] = ((unsigned)row_l << 16) | (unsigned)code;
        }
    }
    __syncthreads();

    // ---- rescore survivors: fp64 dot (z re-read from global) -> fp32 ref sim ----
    {
        int n = lcnt[wv]; if (n > LISTCAP) n = LISTCAP;
        for (int base = 0; base < n; base += 4) {
            int it = base + l4;
            if (it < n) {
                unsigned meta = lmeta[wv * LISTCAP + it];
                int row  = (int)(meta >> 16);
                int code = (int)(meta & 1023u);
                const float* xr = xb + row;            // element c at xr[c*HW]
                const float* er = cb + code * C_DIM;
                double acc = 0.0;
                #pragma unroll
                for (int s2 = 0; s2 < 16; s2++) {
                    int c = l15 + 16 * s2;
                    acc = fma((double)xr[(size_t)c * HW], (double)er[c], acc);
                }
                acc += __shfl_xor(acc, 1, 64);
                acc += __shfl_xor(acc, 2, 64);
                acc += __shfl_xor(acc, 4, 64);
                acc += __shfl_xor(acc, 8, 64);
                if (l15 == 0) {
                    float Mf = (float)acc;
                    float t2 = __fadd_rn(__fsub_rn(S32[row], __fmul_rn(2.0f, Mf)), en_lds[code]);
                    unsigned long long pk =
                        ((unsigned long long)__float_as_uint(t2) << 32) | (unsigned long long)(unsigned)code;
                    atomicMin(&res[row], pk);
                }
            }
        }
    }
    __syncthreads();

    if (t < 64) {
        unsigned long long v = res[t];
        int code = (int)(v & 1023u);
        fidx[t] = code;
        idx_out[row0 + t] = (float)code;
        t2_out[row0 + t] = __uint_as_float((unsigned)(v >> 32));
    }

    // ---- quantized output (NCHW) via LDS bounce: coalesced reads AND stores ----
    float* ob = out + b * (C_DIM * HW) + hw0;
    #pragma unroll
    for (int half = 0; half < 2; half++) {
        __syncthreads();   // fidx ready (first); prior half's stores done (second)
        for (int idx = t; idx < 32 * 64; idx += 512) {
            int r  = idx >> 6;         // 0..31
            int c4 = idx & 63;
            const float* er = cb + fidx[half * 32 + r] * C_DIM;
            *(float4*)&qt[r * QT_STRIDE + c4 * 4] = *(const float4*)(er + c4 * 4);
        }
        __syncthreads();
        int rr = t & 31;
        int cg = t >> 5;               // 0..15
        for (int cc = cg; cc < C_DIM; cc += 16) {
            ob[cc * HW + half * 32 + rr] = qt[rr * QT_STRIDE + cc];
        }
    }
}

// Kernel 3: deterministic loss reduction over per-row t2
__global__ void loss_kernel(const float* __restrict__ t2min, float* __restrict__ losses) {
    __shared__ double sh[256];
    int t = threadIdx.x;
    double a = 0.0;
    const int per = N_ROWS / 256;
    for (int i = t * per; i < t * per + per; i++) a += (double)t2min[i];
    sh[t] = a;
    __syncthreads();
    for (int s = 128; s > 0; s >>= 1) {
        if (t < s) sh[t] += sh[t + s];
        __syncthreads();
    }
    if (t == 0) {
        double M = sh[0] / (double)OUT_ELEMS;
        losses[0] = (float)(1.25 * M);   // quantizer_loss
        losses[1] = (float)(0.25 * M);   // e_latent_loss
        losses[2] = (float)(M);          // q_latent_loss
    }
}

extern "C" void kernel_launch(void* const* d_in, const int* in_sizes, int n_in,
                              void* d_out, int out_size, void* d_ws, size_t ws_size,
                              hipStream_t stream) {
    const float* x  = (const float*)d_in[0];
    const float* cb = (const float*)d_in[1];
    float* out     = (float*)d_out;
    float* losses  = out + LOSS_OFF;
    float* idx_out = out + IDX_OFF;

    char*  cb16     = (char*)d_ws;                               // 524288 B
    float* t2ws     = (float*)((char*)d_ws + 524288);            // 131072 B
    float* enorm_ws = (float*)((char*)d_ws + 524288 + 131072);   // 4096 B

    hipFuncSetAttribute(reinterpret_cast<const void*>(vq_main),
                        hipFuncAttributeMaxDynamicSharedMemorySize, SMEM_BYTES);

    prep_kernel<<<K_CODES / 4, 256, 0, stream>>>(cb, enorm_ws, cb16);
    vq_main<<<N_ROWS / ROWS, 512, SMEM_BYTES, stream>>>(x, cb, enorm_ws, cb16, out, idx_out, t2ws);
    loss_kernel<<<1, 256, 0, stream>>>(t2ws, losses);
}